// Round 5
// baseline (131.500 us; speedup 1.0000x reference)
//
#include <hip/hip_runtime.h>
#include <math.h>

// MatchNet: 4-layer tanh MLP (6->20->20->20->8) + 150-iter PDHG QP solve.
// Round-5 structure: 8 LANES PER SAMPLE (262144 threads = 4096 waves = 4/SIMD)
// to fix the real bottleneck: at 1 thread/sample there were only 2 waves/CU,
// so wall time == one wave's dependent-issue latency (~8cy/instr, invariant
// across rounds 1-4). Lane g owns x-component g and constraint g (g<6).
// Cross-lane: S^T*l1 and S*xbar via ds_bpermute (precomputed nibble-table
// indices); ||v||^2 8-lane reduction via DPP adds (no LDS pipe).
// MLP computed redundantly by all 8 lanes (issue-bound dense FMA, cheap at
// 4 waves/SIMD); lane then selects its z_g via cndmask tree.

#define NITERS 150

__device__ __forceinline__ float ftanh(float a) {
    float e = __expf(2.0f * a);
    return fmaf(-2.0f, __builtin_amdgcn_rcpf(e + 1.0f), 1.0f);
}

template<int CTRL>
__device__ __forceinline__ float dpp_add(float x) {
    int xi = __builtin_bit_cast(int, x);
    int yi = __builtin_amdgcn_update_dpp(0, xi, CTRL, 0xF, 0xF, true);
    return x + __builtin_bit_cast(float, yi);
}

__device__ __forceinline__ float bperm(int addr, float v) {
    return __builtin_bit_cast(float,
        __builtin_amdgcn_ds_bpermute(addr, __builtin_bit_cast(int, v)));
}

#define FOR20(M) M(0) M(1) M(2) M(3) M(4) M(5) M(6) M(7) M(8) M(9) \
                 M(10) M(11) M(12) M(13) M(14) M(15) M(16) M(17) M(18) M(19)
#define FOR8(M)  M(0) M(1) M(2) M(3) M(4) M(5) M(6) M(7)

#define DOT20(W, base, H) \
  ( (fmaf(W[(base)+0],H##0,  fmaf(W[(base)+1],H##1,  fmaf(W[(base)+2],H##2,  fmaf(W[(base)+3],H##3,  W[(base)+4]*H##4)))) \
   + fmaf(W[(base)+5],H##5,  fmaf(W[(base)+6],H##6,  fmaf(W[(base)+7],H##7,  fmaf(W[(base)+8],H##8,  W[(base)+9]*H##9))))) \
  + (fmaf(W[(base)+10],H##10, fmaf(W[(base)+11],H##11, fmaf(W[(base)+12],H##12, fmaf(W[(base)+13],H##13, W[(base)+14]*H##14)))) \
   + fmaf(W[(base)+15],H##15, fmaf(W[(base)+16],H##16, fmaf(W[(base)+17],H##17, fmaf(W[(base)+18],H##18, W[(base)+19]*H##19))))) )

#define DOT6(W, base, P) \
  ( fmaf(W[(base)+0],P##0, fmaf(W[(base)+1],P##1, W[(base)+2]*P##2)) \
  + fmaf(W[(base)+3],P##3, fmaf(W[(base)+4],P##4, W[(base)+5]*P##5)) )

__global__ __launch_bounds__(256, 4)
void matchnet_kernel(
    const float* __restrict__ X,
    const float* __restrict__ W1, const float* __restrict__ b1,
    const float* __restrict__ W2, const float* __restrict__ b2,
    const float* __restrict__ W3, const float* __restrict__ b3,
    const float* __restrict__ W4, const float* __restrict__ b4,
    float* __restrict__ out, int B)
{
    const int tid = blockIdx.x * 256 + threadIdx.x;
    const int s   = tid >> 3;       // sample
    if (s >= B) return;
    const int g   = tid & 7;        // owned component

    const float TAU = 0.9f / sqrtf(26.0f);   // L = sqrt(sum(S*S)+ns)
    const float SIG = TAU;
    const float TS  = TAU * SIG;

    // ---- load sample (8 lanes of a group read the same 6 floats) ----
    float zin0, zin1, zin2, zin3, zin4, zin5;
    {
        const float2* xp = (const float2*)(X + (size_t)s * 6);
        float2 p0 = xp[0], p1 = xp[1], p2 = xp[2];
        zin0 = p0.x; zin1 = p0.y; zin2 = p1.x;
        zin3 = p1.y; zin4 = p2.x; zin5 = p2.y;
    }

    // ---- MLP (redundant across the 8 lanes; dense independent FMA) ----
#define L1ROW(j) float h1_##j = ftanh(b1[j] + DOT6(W1, (j)*6, zin));
    FOR20(L1ROW)
#define L2ROW(j) float h2_##j = ftanh(b2[j] + DOT20(W2, (j)*20, h1_));
    FOR20(L2ROW)
#define L3ROW(j) float h3_##j = ftanh(b3[j] + DOT20(W3, (j)*20, h2_));
    FOR20(L3ROW)
#define ZROW(j)  float z##j  = ftanh(b4[j] + DOT20(W4, (j)*20, h3_));
    FOR8(ZROW)

    // ---- select this lane's z_g and zin_g (cndmask trees) ----
    const bool gb0 = (g & 1), gb1 = (g & 2), gb2 = (g & 4);
    float z01 = gb0 ? z1 : z0;
    float z23 = gb0 ? z3 : z2;
    float z45 = gb0 ? z5 : z4;
    float z67 = gb0 ? z7 : z6;
    float z03 = gb1 ? z23 : z01;
    float z47 = gb1 ? z67 : z45;
    float zg  = gb2 ? z47 : z03;

    float i01 = gb0 ? zin1 : zin0;
    float i23 = gb0 ? zin3 : zin2;
    float i45 = gb0 ? zin5 : zin4;
    float i03 = gb1 ? i23 : i01;
    float ig  = gb2 ? i45 : i03;     // meaningful for g<6 only

    // ---- per-lane PDHG state ----
    float zpt = zg + TAU;                       // z + TAU
    float xz  = fmaxf(zg, 0.0f) - zg + TAU;     // x - z + TAU
    float q   = 0.0f;                           // TAU*l2
    float p   = xz;                             // xz + q
    float l1  = 0.0f;                           // constraint dual (lane g<6)
    float sb  = SIG * ig;

    // ---- cross-lane gather indices (S hardcoded as nibble tables) ----
    // S^T cols: 0:{0,3} 1:{1,4} 2:{2,5} 3:{0,1,5} 4:{2,3,5} 5:{0,3} 6:{1,4} 7:{2,4}
    // S rows:   0:{0,3,5} 1:{1,3,6} 2:{2,4,7} 3:{0,4,5} 4:{1,6,7} 5:{2,3,4}
    const int wl  = threadIdx.x & 63;
    const int gbase = wl & 56;
    const int nib = g * 4;
    const int aStA = (gbase + ((0x21020210u >> nib) & 7)) << 2;
    const int aStB = (gbase + ((0x44331543u >> nib) & 7)) << 2;
    const int aStC = (gbase + ((0x00055000u >> nib) & 7)) << 2;
    const int aRA  = (gbase + ((0x00210210u >> nib) & 7)) << 2;
    const int aRB  = (gbase + ((0x00364433u >> nib) & 7)) << 2;
    const int aRC  = (gbase + ((0x00475765u >> nib) & 7)) << 2;
    const float cm = (g == 3 || g == 4) ? 1.0f : 0.0f;  // 3rd S^T term mask

#pragma unroll 1
    for (int it = 0; it < NITERS; ++it) {
        // st = (S^T l1)_g : 3 bpermutes + masked add
        float s1 = bperm(aStA, l1);
        float s2 = bperm(aStB, l1);
        float s3 = bperm(aStC, l1);
        float st = fmaf(cm, s3, s1 + s2);

        // v = xz - TAU*st + TAU*l2 = fma(-TAU, st, p)
        float v = fmaf(-TAU, st, p);

        // ||v||^2 over the 8-lane group: DPP butterfly (xor1, xor2, mirror8)
        float nv = v * v;
        nv = dpp_add<0xB1>(nv);    // quad_perm [1,0,3,2]  (xor 1)
        nv = dpp_add<0x4E>(nv);    // quad_perm [2,3,0,1]  (xor 2)
        nv = dpp_add<0x141>(nv);   // row_half_mirror      (other quad)

        float scale = fmaxf(fmaf(-TAU, __builtin_amdgcn_rsqf(nv), 1.0f), 0.0f);

        // xb = 2*x_new - x = fma(2*scale, v, zpt - xz); xz' = fma(scale,v,TAU)
        float xb = fmaf(scale + scale, v, zpt - xz);
        xz = fmaf(scale, v, TAU);
        q  = fmaxf(fmaf(-TS, xb, q), 0.0f);
        p  = xz + q;

        // r = (S xb)_g : 3 bpermutes (rows all have exactly 3 terms)
        float r1 = bperm(aRA, xb);
        float r2 = bperm(aRB, xb);
        float r3 = bperm(aRC, xb);
        float r  = (r1 + r2) + r3;

        l1 = fmaxf(fmaf(SIG, r, l1) - sb, 0.0f);
    }

    // x_g = xz + z - TAU ; out[s*8+g] == out[tid] -> fully coalesced
    out[tid] = xz + zg - TAU;
}

extern "C" void kernel_launch(void* const* d_in, const int* in_sizes, int n_in,
                              void* d_out, int out_size, void* d_ws, size_t ws_size,
                              hipStream_t stream) {
    const float* X  = (const float*)d_in[0];
    const float* W1 = (const float*)d_in[1];
    const float* b1 = (const float*)d_in[2];
    const float* W2 = (const float*)d_in[3];
    const float* b2 = (const float*)d_in[4];
    const float* W3 = (const float*)d_in[5];
    const float* b3 = (const float*)d_in[6];
    const float* W4 = (const float*)d_in[7];
    const float* b4 = (const float*)d_in[8];
    float* out = (float*)d_out;
    const int B = in_sizes[0] / 6;
    const int threads = B * 8;
    const int blocks = (threads + 255) / 256;
    hipLaunchKernelGGL(matchnet_kernel, dim3(blocks), dim3(256), 0, stream,
                       X, W1, b1, W2, b2, W3, b3, W4, b4, out, B);
}

// Round 7
// 114.617 us; speedup vs baseline: 1.1473x; 1.1473x over previous
//
#include <hip/hip_runtime.h>
#include <math.h>

// MatchNet: 4-layer tanh MLP (6->20->20->20->8) + 150-iter PDHG QP solve.
// 4 LANES PER SAMPLE (131072 thr = 2048 waves = 2/SIMD), ALL cross-lane
// traffic via quad_perm DPP (VALU pipe; round 5 proved ds_bpermute
// serializes on the per-CU LDS pipe). Round-6 bug fixed here: DPP is a
// CONVERGENT intrinsic -- putting it inside a divergent ternary made the
// backend run it under a partial exec mask, and DPP reads from inactive
// source lanes return 0 (bound_ctrl=1). All DPPs are now unconditional
// statements; the per-lane choice is a value select (v_cndmask) afterwards.

#define NITERS 150

__device__ __forceinline__ float ftanh(float a) {
    float e = __expf(2.0f * a);
    return fmaf(-2.0f, __builtin_amdgcn_rcpf(e + 1.0f), 1.0f);
}

// quad_perm DPP: lane (q*4+k) reads lane (q*4 + P_k); MUST be called
// unconditionally (full exec) -- see header comment.
template<int P0, int P1, int P2, int P3>
__device__ __forceinline__ float qp(float x) {
    constexpr int ctrl = P0 | (P1 << 2) | (P2 << 4) | (P3 << 6);
    int xi = __builtin_bit_cast(int, x);
    int yi = __builtin_amdgcn_update_dpp(0, xi, ctrl, 0xF, 0xF, true);
    return __builtin_bit_cast(float, yi);
}

#define FOR20(M) M(0) M(1) M(2) M(3) M(4) M(5) M(6) M(7) M(8) M(9) \
                 M(10) M(11) M(12) M(13) M(14) M(15) M(16) M(17) M(18) M(19)
#define FOR8(M)  M(0) M(1) M(2) M(3) M(4) M(5) M(6) M(7)

#define DOT20(W, base, H) \
  ( (fmaf(W[(base)+0],H##0,  fmaf(W[(base)+1],H##1,  fmaf(W[(base)+2],H##2,  fmaf(W[(base)+3],H##3,  W[(base)+4]*H##4)))) \
   + fmaf(W[(base)+5],H##5,  fmaf(W[(base)+6],H##6,  fmaf(W[(base)+7],H##7,  fmaf(W[(base)+8],H##8,  W[(base)+9]*H##9))))) \
  + (fmaf(W[(base)+10],H##10, fmaf(W[(base)+11],H##11, fmaf(W[(base)+12],H##12, fmaf(W[(base)+13],H##13, W[(base)+14]*H##14)))) \
   + fmaf(W[(base)+15],H##15, fmaf(W[(base)+16],H##16, fmaf(W[(base)+17],H##17, fmaf(W[(base)+18],H##18, W[(base)+19]*H##19))))) )

#define DOT6(W, base, P) \
  ( fmaf(W[(base)+0],P##0, fmaf(W[(base)+1],P##1, W[(base)+2]*P##2)) \
  + fmaf(W[(base)+3],P##3, fmaf(W[(base)+4],P##4, W[(base)+5]*P##5)) )

__global__ __launch_bounds__(256, 2)
void matchnet_kernel(
    const float* __restrict__ X,
    const float* __restrict__ W1, const float* __restrict__ b1,
    const float* __restrict__ W2, const float* __restrict__ b2,
    const float* __restrict__ W3, const float* __restrict__ b3,
    const float* __restrict__ W4, const float* __restrict__ b4,
    float* __restrict__ out, int B)
{
    const int tid = blockIdx.x * 256 + threadIdx.x;
    const int s   = tid >> 2;       // sample
    if (s >= B) return;
    const int g   = tid & 3;        // quad lane

    const float TAU = 0.9f / sqrtf(26.0f);
    const float SIG = TAU;
    const float TS  = TAU * SIG;

    // ---- load sample ----
    float zin0, zin1, zin2, zin3, zin4, zin5;
    {
        const float2* xp = (const float2*)(X + (size_t)s * 6);
        float2 p0 = xp[0], p1 = xp[1], p2 = xp[2];
        zin0 = p0.x; zin1 = p0.y; zin2 = p1.x;
        zin3 = p1.y; zin4 = p2.x; zin5 = p2.y;
    }

    // ---- MLP (redundant across the 4 lanes; dense independent FMA) ----
#define L1ROW(j) float h1_##j = ftanh(b1[j] + DOT6(W1, (j)*6, zin));
    FOR20(L1ROW)
#define L2ROW(j) float h2_##j = ftanh(b2[j] + DOT20(W2, (j)*20, h1_));
    FOR20(L2ROW)
#define L3ROW(j) float h3_##j = ftanh(b3[j] + DOT20(W3, (j)*20, h2_));
    FOR20(L3ROW)
#define ZROW(j)  float z##j  = ftanh(b4[j] + DOT20(W4, (j)*20, h3_));
    FOR8(ZROW)

    // ---- per-lane selects: zA = z_g, zB = z_{4+g}, sbA/sbB ----
    const bool b0 = (g & 1), b1_ = (g & 2);
    float z01 = b0 ? z1 : z0,  z23 = b0 ? z3 : z2;
    float zA  = b1_ ? z23 : z01;
    float z45 = b0 ? z5 : z4,  z67 = b0 ? z7 : z6;
    float zB  = b1_ ? z67 : z45;

    float i01 = b0 ? zin1 : zin0, i23 = b0 ? zin3 : zin2;
    float igA = b1_ ? i23 : i01;            // zin_g
    float i45 = b0 ? zin5 : zin4;           // zin_{4+g} for g<2
    float sbA = SIG * igA;
    float sbB = (g < 2) ? SIG * i45 : 1e30f;  // 1e30 pins dummy l1B to 0

    // ---- PDHG state ----
    float zptA = zA + TAU, zptB = zB + TAU;
    float xzA  = fmaxf(zA, 0.0f) - zA + TAU;
    float xzB  = fmaxf(zB, 0.0f) - zB + TAU;
    float qA = 0.0f, qB = 0.0f;
    float pA = xzA,  pB = xzB;
    float lA = 0.0f, lB = 0.0f;   // l1_g | l1_{4+g} (lanes 0,1), dummy (2,3)

    const bool sel03 = (g == 0) || (g == 3);
    const bool sel01 = (g < 2);
    const bool sel1  = (g == 1);

#pragma unroll 1
    for (int it = 0; it < NITERS; ++it) {
        // ---- st = S^T l1 ----
        // stA (cols 0-3): lane sets {0,3},{1,4},{2,5},{0,1,5}
        float gA1  = qp<0,1,2,0>(lA);        // [l0,l1,l2,l0]
        float gA2a = qp<3,0,0,1>(lA);        // lanes 0,3 want lA[3],lA[1]
        float gA2b = qp<0,0,1,0>(lB);        // lanes 1,2 want lB[0],lB[1]
        float gA2  = sel03 ? gA2a : gA2b;    // [l3,l4,l5,l1]
        float gA3  = qp<2,2,2,1>(lB);        // [0,0,0,l5]
        float stA = (gA1 + gA2) + gA3;
        // stB (cols 4-7): {2,3,5},{0,3},{1,4},{2,4}
        float gB1  = qp<2,0,1,2>(lA);        // [l2,l0,l1,l2]
        float gB2a = qp<3,3,0,0>(lA);
        float gB2b = qp<0,0,0,0>(lB);
        float gB2  = sel01 ? gB2a : gB2b;    // [l3,l3,l4,l4]
        float gB3  = qp<1,2,2,2>(lB);        // [l5,0,0,0]
        float stB = (gB1 + gB2) + gB3;

        float vA = fmaf(-TAU, stA, pA);
        float vB = fmaf(-TAU, stB, pB);

        // ---- ||v||^2 over quad (DPP xor butterfly) ----
        float nl = fmaf(vA, vA, vB * vB);
        nl = nl + qp<1,0,3,2>(nl);
        nl = nl + qp<2,3,0,1>(nl);
        float scale = fmaxf(fmaf(-TAU, __builtin_amdgcn_rsqf(nl), 1.0f), 0.0f);
        float ss2 = scale + scale;

        // ---- component updates ----
        float xbA = fmaf(ss2, vA, zptA - xzA);
        float xbB = fmaf(ss2, vB, zptB - xzB);
        xzA = fmaf(scale, vA, TAU);
        xzB = fmaf(scale, vB, TAU);
        qA  = fmaxf(fmaf(-TS, xbA, qA), 0.0f);
        qB  = fmaxf(fmaf(-TS, xbB, qB), 0.0f);
        pA  = xzA + qA;
        pB  = xzB + qB;

        // ---- r = S * xbar ----
        // rA (rows 0-3): {0,3,5},{1,3,6},{2,4,7},{0,4,5}  (xbA=x0-3, xbB=x4-7)
        float h1  = qp<0,1,2,0>(xbA);        // [A0,A1,A2,A0]
        float h2a = qp<3,3,0,0>(xbA);
        float h2b = qp<0,0,0,0>(xbB);
        float h2  = sel01 ? h2a : h2b;       // [A3,A3,B0,B0]
        float h3  = qp<1,2,3,1>(xbB);        // [B1,B2,B3,B1]
        float rA = (h1 + h2) + h3;
        // rB (rows 4,5 on lanes 0,1): {1,6,7},{2,3,4}; lanes 2,3 don't-care
        float k1  = qp<1,2,0,0>(xbA);        // [A1,A2,.,.]
        float k2a = qp<0,3,0,0>(xbA);
        float k2b = qp<2,0,0,0>(xbB);
        float k2  = sel1 ? k2a : k2b;        // [B2,A3,.,.]
        float k3  = qp<3,0,0,0>(xbB);        // [B3,B0,.,.]
        float rB = (k1 + k2) + k3;

        lA = fmaxf(fmaf(SIG, rA, lA) - sbA, 0.0f);
        lB = fmaxf(fmaf(SIG, rB, lB) - sbB, 0.0f);  // lanes 2,3 clamp to 0
    }

    // x = xz + z - TAU = xz + zpt - 2*TAU
    const float T2 = 2.0f * TAU;
    out[(size_t)s * 8 + g]     = xzA + zptA - T2;
    out[(size_t)s * 8 + 4 + g] = xzB + zptB - T2;
}

extern "C" void kernel_launch(void* const* d_in, const int* in_sizes, int n_in,
                              void* d_out, int out_size, void* d_ws, size_t ws_size,
                              hipStream_t stream) {
    const float* X  = (const float*)d_in[0];
    const float* W1 = (const float*)d_in[1];
    const float* b1 = (const float*)d_in[2];
    const float* W2 = (const float*)d_in[3];
    const float* b2 = (const float*)d_in[4];
    const float* W3 = (const float*)d_in[5];
    const float* b3 = (const float*)d_in[6];
    const float* W4 = (const float*)d_in[7];
    const float* b4 = (const float*)d_in[8];
    float* out = (float*)d_out;
    const int B = in_sizes[0] / 6;
    const int threads = B * 4;
    const int blocks = (threads + 255) / 256;
    hipLaunchKernelGGL(matchnet_kernel, dim3(blocks), dim3(256), 0, stream,
                       X, W1, b1, W2, b2, W3, b3, W4, b4, out, B);
}